// Round 10
// baseline (2295.209 us; speedup 1.0000x reference)
//
#include <hip/hip_runtime.h>
#include <hip/hip_bf16.h>
#include <cstdint>
#include <cstddef>

// ---------------------------------------------------------------------------
// Cross attention, B=8 N=1024 C=768 HEADS=8 HD=96, sr_ratio=1 path.
//   1. cvt_all: single launch; x,y -> bf16; Wq*QSC, Wk, Wv, Wp -> bf16
//   2. qkv_kernel: 128x96 tiles, 1024 blocks = 4/CU at 2-resident (R16).
//      Q blocks + fused KV blocks (shared y-tile, dual B). n-tile == head.
//   3. flash attention (R17): R7 structure + XCD decode + setprio, PLUS
//      rel prefetch moved to tile top with double-buffered relv regs --
//      the old mid-tile loadrel left only ~300cy (PV) before the barrier's
//      vmcnt(0) drain; 900cy HBM latency => ~500cy/tile stall. Now it has
//      the full tile to land. +32 VGPR (cap 256 at (256,2), no spill).
//   4. proj GEMM: 128x96 tiles, 512 blocks = 2/CU (R15), shared gemm96_core.
// ---------------------------------------------------------------------------

using f32x4  = __attribute__((ext_vector_type(4))) float;
using bf16x8 = __attribute__((ext_vector_type(8))) __bf16;

constexpr int Bb = 8, Nn = 1024, Cc = 768;
constexpr float LOG2E = 1.4426950408889634f;
constexpr float QSC   = 0.10206207261596575f * 1.4426950408889634f;  // SCALE*log2e

__device__ __forceinline__ uint16_t f2bf(float f) {
  union { float f; uint32_t u; } v; v.f = f;
  return (uint16_t)((v.u + 0x7fffu + ((v.u >> 16) & 1u)) >> 16);  // RNE
}

__device__ __forceinline__ void gl_lds16(const void* g, void* l) {
  __builtin_amdgcn_global_load_lds(
      (const __attribute__((address_space(1))) void*)g,
      (__attribute__((address_space(3))) void*)l, 16, 0, 0);
}

__device__ __forceinline__ f32x4 mfma16(bf16x8 a, bf16x8 b, f32x4 c) {
  return __builtin_amdgcn_mfma_f32_16x16x32_bf16(a, b, c, 0, 0, 0);
}

// DPP row_ror sum over a 16-lane row (epilogue only)
template <int CTRL>
__device__ __forceinline__ float dpp_add(float v) {
  union { float f; int i; } u, r;
  u.f = v;
  r.i = __builtin_amdgcn_update_dpp(u.i, u.i, CTRL, 0xF, 0xF, false);
  return v + r.f;
}
__device__ __forceinline__ float red16_add(float v) {
  v = dpp_add<0x128>(v);  // row_ror:8
  v = dpp_add<0x124>(v);  // row_ror:4
  v = dpp_add<0x122>(v);  // row_ror:2
  v = dpp_add<0x121>(v);  // row_ror:1
  return v;
}

// ---------------------------------------------------------------------------
// Single conversion launch for all six tensors (flat-indexed in float4s).
constexpr int NX4 = (Bb * Nn * Cc) / 4;  // 1572864
constexpr int NW4 = (Cc * Cc) / 4;       // 147456
__global__ void cvt_all(const float* __restrict__ x, const float* __restrict__ y,
                        const float* __restrict__ wq, const float* __restrict__ wk,
                        const float* __restrict__ wv, const float* __restrict__ wp,
                        uint16_t* __restrict__ xb, uint16_t* __restrict__ yb,
                        uint16_t* __restrict__ dq, uint16_t* __restrict__ dk,
                        uint16_t* __restrict__ dv, uint16_t* __restrict__ dp) {
  int i = blockIdx.x * blockDim.x + threadIdx.x;
  const float* s; uint16_t* d; int off; float sc = 1.f;
  if (i < NX4) {
    s = x; d = xb; off = i;
  } else if (i < 2 * NX4) {
    s = y; d = yb; off = i - NX4;
  } else {
    int j = i - 2 * NX4;
    int wsel = j / NW4;
    off = j - wsel * NW4;
    switch (wsel) {
      case 0:  s = wq; d = dq; sc = QSC; break;
      case 1:  s = wk; d = dk; break;
      case 2:  s = wv; d = dv; break;
      default: s = wp; d = dp; break;
    }
  }
  float4 v = ((const float4*)s)[off];
  ushort4 o;
  o.x = f2bf(v.x * sc); o.y = f2bf(v.y * sc);
  o.z = f2bf(v.z * sc); o.w = f2bf(v.w * sc);
  ((ushort4*)d)[off] = o;
}

// ---------------------------------------------------------------------------
// GEMM core, 128x96 tile, BK=64, XOR-swizzled LDS, 2-barrier K-loop.
// Per wave: acc[4][3] (64x48 output), per K-step 7 staged chunks : 24 MFMA.
__device__ __forceinline__ void gemm96_core(const uint16_t* __restrict__ A,
                                            const uint16_t* __restrict__ Bt,
                                            uint16_t* As, uint16_t* Bs,
                                            int m0, int n0,
                                            f32x4 (&acc)[4][3]) {
  const int tid = threadIdx.x;
  const int lane = tid & 63, l16 = lane & 15, quad = lane >> 4;
  const int w = tid >> 6;
  const int wm = (w & 1) * 64, wn = (w >> 1) * 48;

  int soffA[4], soffB[3];
#pragma unroll
  for (int i = 0; i < 4; ++i) {
    int idx = tid + 256 * i;           // 1024 A chunks (128 rows x 8)
    int row = idx >> 3, pc = idx & 7;
    soffA[i] = row * 768 + (pc ^ (row & 7)) * 8;
  }
#pragma unroll
  for (int i = 0; i < 3; ++i) {
    int idx = tid + 256 * i;           // 768 B chunks (96 rows x 8)
    int row = idx >> 3, pc = idx & 7;
    soffB[i] = row * 768 + (pc ^ (row & 7)) * 8;
  }

  for (int k0 = 0; k0 < 768; k0 += 64) {
    __syncthreads();
#pragma unroll
    for (int i = 0; i < 4; ++i)
      gl_lds16(A + (size_t)m0 * 768 + k0 + soffA[i], &As[(tid + 256 * i) * 8]);
#pragma unroll
    for (int i = 0; i < 3; ++i)
      gl_lds16(Bt + (size_t)n0 * 768 + k0 + soffB[i], &Bs[(tid + 256 * i) * 8]);
    __syncthreads();
#pragma unroll
    for (int ks = 0; ks < 2; ++ks) {
      bf16x8 a[4], b[3];
      const int phys = (ks * 4 + quad) ^ (l16 & 7);
#pragma unroll
      for (int i = 0; i < 4; ++i)
        a[i] = *(const bf16x8*)&As[(wm + i * 16 + l16) * 64 + phys * 8];
#pragma unroll
      for (int j = 0; j < 3; ++j)
        b[j] = *(const bf16x8*)&Bs[(wn + j * 16 + l16) * 64 + phys * 8];
#pragma unroll
      for (int i = 0; i < 4; ++i)
#pragma unroll
        for (int j = 0; j < 3; ++j)
          acc[i][j] = mfma16(a[i], b[j], acc[i][j]);
    }
  }
}

// ---------------------------------------------------------------------------
// Fused Q/KV projections, 128x96 tiles. Flat grid 1024, XCD-banded:
//   xcd = id&7, jj = id>>3 (0..127); mt = xcd*8 + (jj&7) (0..63);
//   rest = jj>>3 (0..15): kind = rest>>3 (0=Q, 1=fused KV), nb = rest&7.
// 1024 blocks = 4/CU at 2-resident -> two full rounds, 100% packing.
// n0 = nb*96 == head boundary -> V epilogue decode is trivial (h = nb).
__global__ __launch_bounds__(256, 2) void qkv_kernel(
    const uint16_t* __restrict__ xb, const uint16_t* __restrict__ yb,
    const uint16_t* __restrict__ wq, const uint16_t* __restrict__ wk,
    const uint16_t* __restrict__ wv, uint16_t* __restrict__ Qb,
    uint16_t* __restrict__ Kb, uint16_t* __restrict__ Vt) {
  __shared__ uint16_t smem[20480];  // 40 KB: A(16K) + Bk(12K) + Bv(12K)
  const int id = blockIdx.x;
  const int xcd = id & 7, jj = id >> 3;
  const int mt = xcd * 8 + (jj & 7);
  const int rest = jj >> 3;          // 0..15
  const int kind = rest >> 3, nb = rest & 7;
  const int m0 = mt * 128, n0 = nb * 96;

  const int tid = threadIdx.x, lane = tid & 63;
  const int l16 = lane & 15, quad = lane >> 4, w = tid >> 6;
  const int wm = (w & 1) * 64, wn = (w >> 1) * 48;

  if (kind == 0) {
    // ---- Q: 128x96 GEMM, direct bf16 store ----
    f32x4 acc[4][3] = {};
    gemm96_core(xb, wq, smem, smem + 8192, m0, n0, acc);
#pragma unroll
    for (int i = 0; i < 4; ++i)
#pragma unroll
      for (int j = 0; j < 3; ++j) {
        int col = n0 + wn + j * 16 + l16;
#pragma unroll
        for (int r = 0; r < 4; ++r) {
          int row = m0 + wm + i * 16 + quad * 4 + r;
          Qb[(size_t)row * 768 + col] = f2bf(acc[i][j][r]);
        }
      }
    return;
  }

  // ---- fused KV: stage y once, two B tiles, dual accumulators ----
  uint16_t* As = smem;
  uint16_t* Bk = smem + 8192;
  uint16_t* Bv = smem + 14336;

  int soffA[4], soffB[3];
#pragma unroll
  for (int i = 0; i < 4; ++i) {
    int idx = tid + 256 * i;
    int row = idx >> 3, pc = idx & 7;
    soffA[i] = row * 768 + (pc ^ (row & 7)) * 8;
  }
#pragma unroll
  for (int i = 0; i < 3; ++i) {
    int idx = tid + 256 * i;
    int row = idx >> 3, pc = idx & 7;
    soffB[i] = row * 768 + (pc ^ (row & 7)) * 8;
  }

  f32x4 ak[4][3] = {}, av[4][3] = {};
  for (int k0 = 0; k0 < 768; k0 += 64) {
    __syncthreads();
#pragma unroll
    for (int i = 0; i < 4; ++i)
      gl_lds16(yb + (size_t)m0 * 768 + k0 + soffA[i], &As[(tid + 256 * i) * 8]);
#pragma unroll
    for (int i = 0; i < 3; ++i)
      gl_lds16(wk + (size_t)n0 * 768 + k0 + soffB[i], &Bk[(tid + 256 * i) * 8]);
#pragma unroll
    for (int i = 0; i < 3; ++i)
      gl_lds16(wv + (size_t)n0 * 768 + k0 + soffB[i], &Bv[(tid + 256 * i) * 8]);
    __syncthreads();

#pragma unroll
    for (int ks = 0; ks < 2; ++ks) {
      bf16x8 a[4], bk[3], bv[3];
      const int phys = (ks * 4 + quad) ^ (l16 & 7);
#pragma unroll
      for (int i = 0; i < 4; ++i)
        a[i] = *(const bf16x8*)&As[(wm + i * 16 + l16) * 64 + phys * 8];
#pragma unroll
      for (int j = 0; j < 3; ++j) {
        bk[j] = *(const bf16x8*)&Bk[(wn + j * 16 + l16) * 64 + phys * 8];
        bv[j] = *(const bf16x8*)&Bv[(wn + j * 16 + l16) * 64 + phys * 8];
      }
#pragma unroll
      for (int i = 0; i < 4; ++i)
#pragma unroll
        for (int j = 0; j < 3; ++j) {
          ak[i][j] = mfma16(a[i], bk[j], ak[i][j]);
          av[i][j] = mfma16(a[i], bv[j], av[i][j]);
        }
    }
  }

  // K epilogue: direct bf16 store
#pragma unroll
  for (int i = 0; i < 4; ++i)
#pragma unroll
    for (int j = 0; j < 3; ++j) {
      int col = n0 + wn + j * 16 + l16;
#pragma unroll
      for (int r = 0; r < 4; ++r) {
        int row = m0 + wm + i * 16 + quad * 4 + r;
        Kb[(size_t)row * 768 + col] = f2bf(ak[i][j][r]);
      }
    }

  // V epilogue: transpose in LDS (stride 130 pad), coalesced b128 stores.
  // n-tile == head: h = nb, hd = nl (0..95). 96*130 u16 = 24.4 KB <= 40 KB.
  __syncthreads();  // all LDS reads of the K-loop done; smem reusable
#pragma unroll
  for (int i = 0; i < 4; ++i)
#pragma unroll
    for (int j = 0; j < 3; ++j) {
      int ml = wm + i * 16 + quad * 4;   // local m (4 consecutive rows)
      int nl = wn + j * 16 + l16;        // local channel 0..95
      ushort4 pk;
      pk.x = f2bf(av[i][j][0]); pk.y = f2bf(av[i][j][1]);
      pk.z = f2bf(av[i][j][2]); pk.w = f2bf(av[i][j][3]);
      *(ushort4*)&smem[nl * 130 + ml] = pk;  // T[n][m], m-contiguous
    }
  __syncthreads();
  const int bidx = m0 >> 10, nseq0 = m0 & 1023;
#pragma unroll
  for (int pass = 0; pass < 6; ++pass) {
    int nl = pass * 16 + (tid >> 4);     // local channel 0..95
    int m = (tid & 15) * 8;              // m-chunk base
    bf16x8 v = *(const bf16x8*)&smem[nl * 130 + m];
    size_t o = (((size_t)(bidx * 8 + nb) * 96 + nl) << 10) + nseq0 + m;
    *(bf16x8*)(Vt + o) = v;              // 16 lanes x 16B contiguous
  }
}

// Output projection: 128x96 tiles via gemm96_core, flat grid 512 = 2/CU
// (XCD-banded: mt = xcd*8 + (jj&7) 0..63, nb = jj>>3 0..7; n0 = nb*96).
__global__ __launch_bounds__(256, 2) void proj_kernel(
    const uint16_t* __restrict__ A, const uint16_t* __restrict__ Bt,
    float* __restrict__ out, const float* __restrict__ bias) {
  __shared__ uint16_t smem[14336];    // 28 KB: As(16K) + Bs(12K)
  const int id = blockIdx.x;
  const int xcd = id & 7, jj = id >> 3;   // jj 0..63
  const int mt = xcd * 8 + (jj & 7);      // 0..63
  const int nb = jj >> 3;                 // 0..7
  const int m0 = mt * 128, n0 = nb * 96;
  const int tid = threadIdx.x, lane = tid & 63;
  const int l16 = lane & 15, quad = lane >> 4, w = tid >> 6;
  const int wm = (w & 1) * 64, wn = (w >> 1) * 48;

  f32x4 acc[4][3] = {};
  gemm96_core(A, Bt, smem, smem + 8192, m0, n0, acc);

  float bv[3];
#pragma unroll
  for (int j = 0; j < 3; ++j) bv[j] = bias[n0 + wn + j * 16 + l16];
#pragma unroll
  for (int i = 0; i < 4; ++i)
#pragma unroll
    for (int j = 0; j < 3; ++j) {
      int col = n0 + wn + j * 16 + l16;
#pragma unroll
      for (int r = 0; r < 4; ++r) {
        int row = m0 + wm + i * 16 + quad * 4 + r;
        out[(size_t)row * 768 + col] = acc[i][j][r] + bv[j];
      }
    }
}

// ---------------------------------------------------------------------------
// Flash attention (R17): R7 structure + XCD decode + setprio + early rel
// prefetch (double-buffered relv, loadrel at tile top so the 900cy HBM
// latency hides under the whole tile, not just PV, before the barrier's
// implicit vmcnt(0) drain). 256 threads, 4 waves x 2 strips, NO-MAX softmax.
__global__ __launch_bounds__(256, 2) void attn_kernel(
    const uint16_t* __restrict__ Q,   // [B][N][C] bf16 (pre-scaled by QSC)
    const uint16_t* __restrict__ Kb,  // [B][N][C] bf16
    const uint16_t* __restrict__ Vt,  // [B*H][HD][N] bf16
    const float* __restrict__ rel,    // [H][N][N] f32
    uint16_t* __restrict__ AO) {      // [B][N][C] bf16
  __shared__ uint16_t Ks[2][64 * 96];   // 2 x 12 KB, mixed-XOR swizzle
  __shared__ uint16_t Vs[2][96 * 64];   // 2 x 12 KB, XOR swizzle
  __shared__ uint16_t Ps[128 * 64];     // 16 KB, XOR-swizzled chunks

  const int tid = threadIdx.x;
  // XCD-chunked bijective decode: swz = (id%8)*64 + id/8; h = swz>>6.
  const int id = blockIdx.x;
  const int swz = (id & 7) * 64 + (id >> 3);
  const int h  = swz >> 6;             // one head per XCD
  const int q0 = ((swz >> 3) & 7) * 128;
  const int b  = swz & 7;              // b fastest: rel-slice sharers adjacent
  const int bh = b * 8 + h;

  const int w = tid >> 6, lane = tid & 63;
  const int l16 = lane & 15, quad = lane >> 4;
  const int l7 = l16 & 7;

  // Q fragments in registers, 2 strips
  bf16x8 qf[2][3];
#pragma unroll
  for (int st = 0; st < 2; ++st) {
    const int qrow = q0 + st * 64 + w * 16 + l16;
    const uint16_t* qp =
        Q + ((size_t)(b * 1024 + qrow)) * 768 + h * 96 + quad * 8;
#pragma unroll
    for (int j = 0; j < 3; ++j) qf[st][j] = *(const bf16x8*)(qp + j * 32);
  }

  auto kSrc = [](int c) {
    int r = c / 12, pc = c % 12;
    int kc = (pc < 8) ? (pc ^ (r & 7)) : (8 + ((pc & 3) ^ (r & 3)));
    return r * 768 + kc * 8;
  };
  auto vSrc = [](int c) {
    int d = c >> 3, pc = c & 7;
    return d * 1024 + (pc ^ (d & 7)) * 8;
  };
  int koffs[3], voffs[3];
#pragma unroll
  for (int i = 0; i < 3; ++i) {
    koffs[i] = kSrc(tid + 256 * i);
    voffs[i] = vSrc(tid + 256 * i);
  }

  const uint16_t* kslab = Kb + ((size_t)(b * 1024)) * 768 + h * 96;
  const uint16_t* vslab = Vt + ((size_t)(bh * 96) << 10);
  const float* relbase0 =
      rel + ((size_t)h << 20) + ((size_t)(q0 + w * 16 + quad * 4) << 10) + l16;
  const float* relbase1 = relbase0 + (64 << 10);

  auto stage = [&](int knext, int bufi) {
    const uint16_t* kb = kslab + (size_t)knext * 768;
    const uint16_t* vb = vslab + knext;
    uint16_t* Kbuf = &Ks[bufi][0];
    uint16_t* Vbuf = &Vs[bufi][0];
#pragma unroll
    for (int i = 0; i < 3; ++i) {
      gl_lds16(kb + koffs[i], Kbuf + (tid + 256 * i) * 8);
      gl_lds16(vb + voffs[i], Vbuf + (tid + 256 * i) * 8);
    }
  };

  // rel bias double-buffer: loadrel(t+1) issues at tile top (full tile of
  // latency cover); two named arrays + explicit parity => static indexing.
  float relvA[2][16], relvB[2][16];
  auto loadrelTo = [&](int knext, float (&dst)[2][16]) {
#pragma unroll
    for (int r = 0; r < 4; ++r)
#pragma unroll
      for (int nt = 0; nt < 4; ++nt) {
        dst[0][nt * 4 + r] = relbase0[(size_t)r * 1024 + knext + nt * 16];
        dst[1][nt * 4 + r] = relbase1[(size_t)r * 1024 + knext + nt * 16];
      }
  };

  float l_i[2][4] = {};
  f32x4 o_acc[2][6] = {};

  stage(0, 0);
  loadrelTo(0, relvA);

  // one K-tile; cur/nxt buffers are compile-time constants per call site
  auto tile = [&](int kt, int bufcur, float (&curR)[2][16],
                  float (&nxtR)[2][16]) {
    __syncthreads();  // staging of cur drained; prior reads of nxt done
    if (kt < 15) {
      stage((kt + 1) * 64, bufcur ^ 1);
      loadrelTo((kt + 1) * 64, nxtR);  // early issue: full tile to land
    }
    const uint16_t* KsC = &Ks[bufcur][0];
    const uint16_t* VsC = &Vs[bufcur][0];

    // S strips (2 x 16q x 64k): each K B-frag read feeds both strips
    f32x4 s[2][4] = {};
    __builtin_amdgcn_s_setprio(1);
#pragma unroll
    for (int ksi = 0; ksi < 3; ++ksi) {
#pragma unroll
      for (int nt = 0; nt < 4; ++nt) {
        const int row = nt * 16 + l16;
        const int c = ksi * 4 + quad;
        const int phys =
            (ksi < 2) ? (c ^ (row & 7)) : (8 + ((c & 3) ^ (row & 3)));
        bf16x8 kf = *(const bf16x8*)&KsC[row * 96 + phys * 8];
        s[0][nt] = mfma16(qf[0][ksi], kf, s[0][nt]);
        s[1][nt] = mfma16(qf[1][ksi], kf, s[1][nt]);
      }
    }
    __builtin_amdgcn_s_setprio(0);

    // softmax (no max) + P scatter per strip; consumes curR[st]
    const int khi = l16 >> 3;
#pragma unroll
    for (int st = 0; st < 2; ++st) {
      float pv[16];
#pragma unroll
      for (int nt = 0; nt < 4; ++nt)
#pragma unroll
        for (int r = 0; r < 4; ++r)
          pv[nt * 4 + r] = __builtin_amdgcn_exp2f(
              fmaf(curR[st][nt * 4 + r], LOG2E, s[st][nt][r]));
#pragma unroll
      for (int r = 0; r < 4; ++r)
        l_i[st][r] += (pv[r] + pv[4 + r]) + (pv[8 + r] + pv[12 + r]);
#pragma unroll
      for (int r = 0; r < 4; ++r) {
        const int qloc = quad * 4 + r;
        const int rowoff = (st * 64 + w * 16 + qloc) * 64;
        const int sw = qloc & 7;
#pragma unroll
        for (int nt = 0; nt < 4; ++nt) {
          const int kc = 2 * nt + khi;
          Ps[rowoff + (((kc ^ sw) << 3) | l7)] = f2bf(pv[nt * 4 + r]);
        }
      }
    }

    asm volatile("s_waitcnt lgkmcnt(0)" ::: "memory");  // wave-internal W->R

    // O strips (2 x 16q x 96d): each V B-frag read feeds both strips
    __builtin_amdgcn_s_setprio(1);
#pragma unroll
    for (int ksi = 0; ksi < 2; ++ksi) {
      const int phys = (ksi * 4 + quad) ^ l7;
      bf16x8 pf0 = *(const bf16x8*)&Ps[(w * 16 + l16) * 64 + phys * 8];
      bf16x8 pf1 = *(const bf16x8*)&Ps[(64 + w * 16 + l16) * 64 + phys * 8];
#pragma unroll
      for (int jt = 0; jt < 6; ++jt) {
        const int d = jt * 16 + l16;
        bf16x8 vf = *(const bf16x8*)&VsC[d * 64 + phys * 8];  // d&7 == l7
        o_acc[0][jt] = mfma16(pf0, vf, o_acc[0][jt]);
        o_acc[1][jt] = mfma16(pf1, vf, o_acc[1][jt]);
      }
    }
    __builtin_amdgcn_s_setprio(0);
  };

  for (int kt2 = 0; kt2 < 16; kt2 += 2) {
    tile(kt2, 0, relvA, relvB);
    tile(kt2 + 1, 1, relvB, relvA);
  }

  // epilogue: one DPP reduction per row, normalize, store bf16
#pragma unroll
  for (int st = 0; st < 2; ++st)
#pragma unroll
    for (int r = 0; r < 4; ++r) {
      float inv = 1.f / red16_add(l_i[st][r]);
      int row = q0 + st * 64 + w * 16 + quad * 4 + r;
#pragma unroll
      for (int jt = 0; jt < 6; ++jt) {
        int col = h * 96 + jt * 16 + l16;
        AO[(size_t)(b * 1024 + row) * 768 + col] = f2bf(o_acc[st][jt][r] * inv);
      }
    }
}

// ---------------------------------------------------------------------------
extern "C" void kernel_launch(void* const* d_in, const int* in_sizes, int n_in,
                              void* d_out, int out_size, void* d_ws,
                              size_t ws_size, hipStream_t stream) {
  const float* x   = (const float*)d_in[0];
  const float* y   = (const float*)d_in[1];
  const float* rel = (const float*)d_in[2];
  const float* Wq  = (const float*)d_in[5];
  const float* Wk  = (const float*)d_in[6];
  const float* Wv  = (const float*)d_in[7];
  const float* Wp  = (const float*)d_in[8];
  const float* bp  = (const float*)d_in[9];
  float* out = (float*)d_out;

  const size_t nBNC = (size_t)Bb * Nn * Cc;  // 6291456
  const size_t nW = (size_t)Cc * Cc;         // 589824

  char* ws = (char*)d_ws;
  size_t off = 0;
  auto alloc = [&](size_t bytes) {
    char* p = ws + off;
    off += (bytes + 255) & ~(size_t)255;
    return p;
  };
  uint16_t* xb  = (uint16_t*)alloc(nBNC * 2);
  uint16_t* yb  = (uint16_t*)alloc(nBNC * 2);
  uint16_t* wqb = (uint16_t*)alloc(nW * 2);
  uint16_t* wkb = (uint16_t*)alloc(nW * 2);
  uint16_t* wvb = (uint16_t*)alloc(nW * 2);
  uint16_t* wpb = (uint16_t*)alloc(nW * 2);
  uint16_t* Qb  = (uint16_t*)alloc(nBNC * 2);
  uint16_t* Kb  = (uint16_t*)alloc(nBNC * 2);
  uint16_t* Vtb = (uint16_t*)alloc(nBNC * 2);
  uint16_t* AOb = (uint16_t*)alloc(nBNC * 2);

  // 1. all conversions, one launch (14592 blocks exactly)
  const int cvtBlocks = (2 * NX4 + 4 * NW4) / 256;
  cvt_all<<<cvtBlocks, 256, 0, stream>>>(x, y, Wq, Wk, Wv, Wp, xb, yb, wqb,
                                         wkb, wvb, wpb);

  // 2. fused Q/KV projections (flat 1024, 128x96 tiles, XCD-banded)
  qkv_kernel<<<dim3(1024), 256, 0, stream>>>(xb, yb, wqb, wkb, wvb, Qb, Kb,
                                             Vtb);

  // 3. attention (flat 512 blocks, 256 threads, R7 + early rel prefetch)
  attn_kernel<<<dim3(512), 256, 0, stream>>>(Qb, Kb, Vtb, rel, AOb);

  // 4. output projection + bias (flat 512, 128x96 tiles, XCD-banded)
  proj_kernel<<<dim3(512), 256, 0, stream>>>(AOb, wpb, out, bp);
}

// Round 11
// 337.982 us; speedup vs baseline: 6.7909x; 6.7909x over previous
//
#include <hip/hip_runtime.h>
#include <hip/hip_bf16.h>
#include <cstdint>
#include <cstddef>

// ---------------------------------------------------------------------------
// Cross attention, B=8 N=1024 C=768 HEADS=8 HD=96, sr_ratio=1 path.
//   1. cvt_all: single launch; x,y -> bf16; Wq*QSC, Wk, Wv, Wp -> bf16
//   2. qkv_kernel: 128x96 tiles, 1024 blocks = 4/CU at 2-resident (R16).
//      Q blocks + fused KV blocks (shared y-tile, dual B). n-tile == head.
//   3. flash attention (R18 = R17 spill-proof): early rel prefetch with
//      double-buffered relv, implemented via TEXTUAL MACRO (direct named
//      array access) -- R17's lambda-with-array-ref-params defeated SROA
//      and spilled both buffers to scratch (4.3 GB WRITE, 2295 us total).
//   4. proj GEMM: 128x96 tiles, 512 blocks = 2/CU (R15), shared gemm96_core.
// ---------------------------------------------------------------------------

using f32x4  = __attribute__((ext_vector_type(4))) float;
using bf16x8 = __attribute__((ext_vector_type(8))) __bf16;

constexpr int Bb = 8, Nn = 1024, Cc = 768;
constexpr float LOG2E = 1.4426950408889634f;
constexpr float QSC   = 0.10206207261596575f * 1.4426950408889634f;  // SCALE*log2e

__device__ __forceinline__ uint16_t f2bf(float f) {
  union { float f; uint32_t u; } v; v.f = f;
  return (uint16_t)((v.u + 0x7fffu + ((v.u >> 16) & 1u)) >> 16);  // RNE
}

__device__ __forceinline__ void gl_lds16(const void* g, void* l) {
  __builtin_amdgcn_global_load_lds(
      (const __attribute__((address_space(1))) void*)g,
      (__attribute__((address_space(3))) void*)l, 16, 0, 0);
}

__device__ __forceinline__ f32x4 mfma16(bf16x8 a, bf16x8 b, f32x4 c) {
  return __builtin_amdgcn_mfma_f32_16x16x32_bf16(a, b, c, 0, 0, 0);
}

// DPP row_ror sum over a 16-lane row (epilogue only)
template <int CTRL>
__device__ __forceinline__ float dpp_add(float v) {
  union { float f; int i; } u, r;
  u.f = v;
  r.i = __builtin_amdgcn_update_dpp(u.i, u.i, CTRL, 0xF, 0xF, false);
  return v + r.f;
}
__device__ __forceinline__ float red16_add(float v) {
  v = dpp_add<0x128>(v);  // row_ror:8
  v = dpp_add<0x124>(v);  // row_ror:4
  v = dpp_add<0x122>(v);  // row_ror:2
  v = dpp_add<0x121>(v);  // row_ror:1
  return v;
}

// ---------------------------------------------------------------------------
// Single conversion launch for all six tensors (flat-indexed in float4s).
constexpr int NX4 = (Bb * Nn * Cc) / 4;  // 1572864
constexpr int NW4 = (Cc * Cc) / 4;       // 147456
__global__ void cvt_all(const float* __restrict__ x, const float* __restrict__ y,
                        const float* __restrict__ wq, const float* __restrict__ wk,
                        const float* __restrict__ wv, const float* __restrict__ wp,
                        uint16_t* __restrict__ xb, uint16_t* __restrict__ yb,
                        uint16_t* __restrict__ dq, uint16_t* __restrict__ dk,
                        uint16_t* __restrict__ dv, uint16_t* __restrict__ dp) {
  int i = blockIdx.x * blockDim.x + threadIdx.x;
  const float* s; uint16_t* d; int off; float sc = 1.f;
  if (i < NX4) {
    s = x; d = xb; off = i;
  } else if (i < 2 * NX4) {
    s = y; d = yb; off = i - NX4;
  } else {
    int j = i - 2 * NX4;
    int wsel = j / NW4;
    off = j - wsel * NW4;
    switch (wsel) {
      case 0:  s = wq; d = dq; sc = QSC; break;
      case 1:  s = wk; d = dk; break;
      case 2:  s = wv; d = dv; break;
      default: s = wp; d = dp; break;
    }
  }
  float4 v = ((const float4*)s)[off];
  ushort4 o;
  o.x = f2bf(v.x * sc); o.y = f2bf(v.y * sc);
  o.z = f2bf(v.z * sc); o.w = f2bf(v.w * sc);
  ((ushort4*)d)[off] = o;
}

// ---------------------------------------------------------------------------
// GEMM core, 128x96 tile, BK=64, XOR-swizzled LDS, 2-barrier K-loop.
// Per wave: acc[4][3] (64x48 output), per K-step 7 staged chunks : 24 MFMA.
__device__ __forceinline__ void gemm96_core(const uint16_t* __restrict__ A,
                                            const uint16_t* __restrict__ Bt,
                                            uint16_t* As, uint16_t* Bs,
                                            int m0, int n0,
                                            f32x4 (&acc)[4][3]) {
  const int tid = threadIdx.x;
  const int lane = tid & 63, l16 = lane & 15, quad = lane >> 4;
  const int w = tid >> 6;
  const int wm = (w & 1) * 64, wn = (w >> 1) * 48;

  int soffA[4], soffB[3];
#pragma unroll
  for (int i = 0; i < 4; ++i) {
    int idx = tid + 256 * i;           // 1024 A chunks (128 rows x 8)
    int row = idx >> 3, pc = idx & 7;
    soffA[i] = row * 768 + (pc ^ (row & 7)) * 8;
  }
#pragma unroll
  for (int i = 0; i < 3; ++i) {
    int idx = tid + 256 * i;           // 768 B chunks (96 rows x 8)
    int row = idx >> 3, pc = idx & 7;
    soffB[i] = row * 768 + (pc ^ (row & 7)) * 8;
  }

  for (int k0 = 0; k0 < 768; k0 += 64) {
    __syncthreads();
#pragma unroll
    for (int i = 0; i < 4; ++i)
      gl_lds16(A + (size_t)m0 * 768 + k0 + soffA[i], &As[(tid + 256 * i) * 8]);
#pragma unroll
    for (int i = 0; i < 3; ++i)
      gl_lds16(Bt + (size_t)n0 * 768 + k0 + soffB[i], &Bs[(tid + 256 * i) * 8]);
    __syncthreads();
#pragma unroll
    for (int ks = 0; ks < 2; ++ks) {
      bf16x8 a[4], b[3];
      const int phys = (ks * 4 + quad) ^ (l16 & 7);
#pragma unroll
      for (int i = 0; i < 4; ++i)
        a[i] = *(const bf16x8*)&As[(wm + i * 16 + l16) * 64 + phys * 8];
#pragma unroll
      for (int j = 0; j < 3; ++j)
        b[j] = *(const bf16x8*)&Bs[(wn + j * 16 + l16) * 64 + phys * 8];
#pragma unroll
      for (int i = 0; i < 4; ++i)
#pragma unroll
        for (int j = 0; j < 3; ++j)
          acc[i][j] = mfma16(a[i], b[j], acc[i][j]);
    }
  }
}

// ---------------------------------------------------------------------------
// Fused Q/KV projections, 128x96 tiles. Flat grid 1024, XCD-banded:
//   xcd = id&7, jj = id>>3 (0..127); mt = xcd*8 + (jj&7) (0..63);
//   rest = jj>>3 (0..15): kind = rest>>3 (0=Q, 1=fused KV), nb = rest&7.
// 1024 blocks = 4/CU at 2-resident -> two full rounds, 100% packing.
// n0 = nb*96 == head boundary -> V epilogue decode is trivial (h = nb).
__global__ __launch_bounds__(256, 2) void qkv_kernel(
    const uint16_t* __restrict__ xb, const uint16_t* __restrict__ yb,
    const uint16_t* __restrict__ wq, const uint16_t* __restrict__ wk,
    const uint16_t* __restrict__ wv, uint16_t* __restrict__ Qb,
    uint16_t* __restrict__ Kb, uint16_t* __restrict__ Vt) {
  __shared__ uint16_t smem[20480];  // 40 KB: A(16K) + Bk(12K) + Bv(12K)
  const int id = blockIdx.x;
  const int xcd = id & 7, jj = id >> 3;
  const int mt = xcd * 8 + (jj & 7);
  const int rest = jj >> 3;          // 0..15
  const int kind = rest >> 3, nb = rest & 7;
  const int m0 = mt * 128, n0 = nb * 96;

  const int tid = threadIdx.x, lane = tid & 63;
  const int l16 = lane & 15, quad = lane >> 4, w = tid >> 6;
  const int wm = (w & 1) * 64, wn = (w >> 1) * 48;

  if (kind == 0) {
    // ---- Q: 128x96 GEMM, direct bf16 store ----
    f32x4 acc[4][3] = {};
    gemm96_core(xb, wq, smem, smem + 8192, m0, n0, acc);
#pragma unroll
    for (int i = 0; i < 4; ++i)
#pragma unroll
      for (int j = 0; j < 3; ++j) {
        int col = n0 + wn + j * 16 + l16;
#pragma unroll
        for (int r = 0; r < 4; ++r) {
          int row = m0 + wm + i * 16 + quad * 4 + r;
          Qb[(size_t)row * 768 + col] = f2bf(acc[i][j][r]);
        }
      }
    return;
  }

  // ---- fused KV: stage y once, two B tiles, dual accumulators ----
  uint16_t* As = smem;
  uint16_t* Bk = smem + 8192;
  uint16_t* Bv = smem + 14336;

  int soffA[4], soffB[3];
#pragma unroll
  for (int i = 0; i < 4; ++i) {
    int idx = tid + 256 * i;
    int row = idx >> 3, pc = idx & 7;
    soffA[i] = row * 768 + (pc ^ (row & 7)) * 8;
  }
#pragma unroll
  for (int i = 0; i < 3; ++i) {
    int idx = tid + 256 * i;
    int row = idx >> 3, pc = idx & 7;
    soffB[i] = row * 768 + (pc ^ (row & 7)) * 8;
  }

  f32x4 ak[4][3] = {}, av[4][3] = {};
  for (int k0 = 0; k0 < 768; k0 += 64) {
    __syncthreads();
#pragma unroll
    for (int i = 0; i < 4; ++i)
      gl_lds16(yb + (size_t)m0 * 768 + k0 + soffA[i], &As[(tid + 256 * i) * 8]);
#pragma unroll
    for (int i = 0; i < 3; ++i)
      gl_lds16(wk + (size_t)n0 * 768 + k0 + soffB[i], &Bk[(tid + 256 * i) * 8]);
#pragma unroll
    for (int i = 0; i < 3; ++i)
      gl_lds16(wv + (size_t)n0 * 768 + k0 + soffB[i], &Bv[(tid + 256 * i) * 8]);
    __syncthreads();

#pragma unroll
    for (int ks = 0; ks < 2; ++ks) {
      bf16x8 a[4], bk[3], bv[3];
      const int phys = (ks * 4 + quad) ^ (l16 & 7);
#pragma unroll
      for (int i = 0; i < 4; ++i)
        a[i] = *(const bf16x8*)&As[(wm + i * 16 + l16) * 64 + phys * 8];
#pragma unroll
      for (int j = 0; j < 3; ++j) {
        bk[j] = *(const bf16x8*)&Bk[(wn + j * 16 + l16) * 64 + phys * 8];
        bv[j] = *(const bf16x8*)&Bv[(wn + j * 16 + l16) * 64 + phys * 8];
      }
#pragma unroll
      for (int i = 0; i < 4; ++i)
#pragma unroll
        for (int j = 0; j < 3; ++j) {
          ak[i][j] = mfma16(a[i], bk[j], ak[i][j]);
          av[i][j] = mfma16(a[i], bv[j], av[i][j]);
        }
    }
  }

  // K epilogue: direct bf16 store
#pragma unroll
  for (int i = 0; i < 4; ++i)
#pragma unroll
    for (int j = 0; j < 3; ++j) {
      int col = n0 + wn + j * 16 + l16;
#pragma unroll
      for (int r = 0; r < 4; ++r) {
        int row = m0 + wm + i * 16 + quad * 4 + r;
        Kb[(size_t)row * 768 + col] = f2bf(ak[i][j][r]);
      }
    }

  // V epilogue: transpose in LDS (stride 130 pad), coalesced b128 stores.
  // n-tile == head: h = nb, hd = nl (0..95). 96*130 u16 = 24.4 KB <= 40 KB.
  __syncthreads();  // all LDS reads of the K-loop done; smem reusable
#pragma unroll
  for (int i = 0; i < 4; ++i)
#pragma unroll
    for (int j = 0; j < 3; ++j) {
      int ml = wm + i * 16 + quad * 4;   // local m (4 consecutive rows)
      int nl = wn + j * 16 + l16;        // local channel 0..95
      ushort4 pk;
      pk.x = f2bf(av[i][j][0]); pk.y = f2bf(av[i][j][1]);
      pk.z = f2bf(av[i][j][2]); pk.w = f2bf(av[i][j][3]);
      *(ushort4*)&smem[nl * 130 + ml] = pk;  // T[n][m], m-contiguous
    }
  __syncthreads();
  const int bidx = m0 >> 10, nseq0 = m0 & 1023;
#pragma unroll
  for (int pass = 0; pass < 6; ++pass) {
    int nl = pass * 16 + (tid >> 4);     // local channel 0..95
    int m = (tid & 15) * 8;              // m-chunk base
    bf16x8 v = *(const bf16x8*)&smem[nl * 130 + m];
    size_t o = (((size_t)(bidx * 8 + nb) * 96 + nl) << 10) + nseq0 + m;
    *(bf16x8*)(Vt + o) = v;              // 16 lanes x 16B contiguous
  }
}

// Output projection: 128x96 tiles via gemm96_core, flat grid 512 = 2/CU
// (XCD-banded: mt = xcd*8 + (jj&7) 0..63, nb = jj>>3 0..7; n0 = nb*96).
__global__ __launch_bounds__(256, 2) void proj_kernel(
    const uint16_t* __restrict__ A, const uint16_t* __restrict__ Bt,
    float* __restrict__ out, const float* __restrict__ bias) {
  __shared__ uint16_t smem[14336];    // 28 KB: As(16K) + Bs(12K)
  const int id = blockIdx.x;
  const int xcd = id & 7, jj = id >> 3;   // jj 0..63
  const int mt = xcd * 8 + (jj & 7);      // 0..63
  const int nb = jj >> 3;                 // 0..7
  const int m0 = mt * 128, n0 = nb * 96;
  const int tid = threadIdx.x, lane = tid & 63;
  const int l16 = lane & 15, quad = lane >> 4, w = tid >> 6;
  const int wm = (w & 1) * 64, wn = (w >> 1) * 48;

  f32x4 acc[4][3] = {};
  gemm96_core(A, Bt, smem, smem + 8192, m0, n0, acc);

  float bv[3];
#pragma unroll
  for (int j = 0; j < 3; ++j) bv[j] = bias[n0 + wn + j * 16 + l16];
#pragma unroll
  for (int i = 0; i < 4; ++i)
#pragma unroll
    for (int j = 0; j < 3; ++j) {
      int col = n0 + wn + j * 16 + l16;
#pragma unroll
      for (int r = 0; r < 4; ++r) {
        int row = m0 + wm + i * 16 + quad * 4 + r;
        out[(size_t)row * 768 + col] = acc[i][j][r] + bv[j];
      }
    }
}

// ---------------------------------------------------------------------------
// Flash attention (R18): R7 structure + XCD decode + setprio + early rel
// prefetch. Double-buffered relv via textual macros -- relvA/relvB always
// accessed by NAME with compile-time indices (no array-ref params: R17's
// lambda form defeated SROA and spilled both buffers to scratch).
__global__ __launch_bounds__(256, 2) void attn_kernel(
    const uint16_t* __restrict__ Q,   // [B][N][C] bf16 (pre-scaled by QSC)
    const uint16_t* __restrict__ Kb,  // [B][N][C] bf16
    const uint16_t* __restrict__ Vt,  // [B*H][HD][N] bf16
    const float* __restrict__ rel,    // [H][N][N] f32
    uint16_t* __restrict__ AO) {      // [B][N][C] bf16
  __shared__ uint16_t Ks[2][64 * 96];   // 2 x 12 KB, mixed-XOR swizzle
  __shared__ uint16_t Vs[2][96 * 64];   // 2 x 12 KB, XOR swizzle
  __shared__ uint16_t Ps[128 * 64];     // 16 KB, XOR-swizzled chunks

  const int tid = threadIdx.x;
  // XCD-chunked bijective decode: swz = (id%8)*64 + id/8; h = swz>>6.
  const int id = blockIdx.x;
  const int swz = (id & 7) * 64 + (id >> 3);
  const int h  = swz >> 6;             // one head per XCD
  const int q0 = ((swz >> 3) & 7) * 128;
  const int b  = swz & 7;              // b fastest: rel-slice sharers adjacent
  const int bh = b * 8 + h;

  const int w = tid >> 6, lane = tid & 63;
  const int l16 = lane & 15, quad = lane >> 4;
  const int l7 = l16 & 7;

  // Q fragments in registers, 2 strips
  bf16x8 qf[2][3];
#pragma unroll
  for (int st = 0; st < 2; ++st) {
    const int qrow = q0 + st * 64 + w * 16 + l16;
    const uint16_t* qp =
        Q + ((size_t)(b * 1024 + qrow)) * 768 + h * 96 + quad * 8;
#pragma unroll
    for (int j = 0; j < 3; ++j) qf[st][j] = *(const bf16x8*)(qp + j * 32);
  }

  auto kSrc = [](int c) {
    int r = c / 12, pc = c % 12;
    int kc = (pc < 8) ? (pc ^ (r & 7)) : (8 + ((pc & 3) ^ (r & 3)));
    return r * 768 + kc * 8;
  };
  auto vSrc = [](int c) {
    int d = c >> 3, pc = c & 7;
    return d * 1024 + (pc ^ (d & 7)) * 8;
  };
  int koffs[3], voffs[3];
#pragma unroll
  for (int i = 0; i < 3; ++i) {
    koffs[i] = kSrc(tid + 256 * i);
    voffs[i] = vSrc(tid + 256 * i);
  }

  const uint16_t* kslab = Kb + ((size_t)(b * 1024)) * 768 + h * 96;
  const uint16_t* vslab = Vt + ((size_t)(bh * 96) << 10);
  const float* relbase0 =
      rel + ((size_t)h << 20) + ((size_t)(q0 + w * 16 + quad * 4) << 10) + l16;
  const float* relbase1 = relbase0 + (64 << 10);

  auto stage = [&](int knext, int bufi) {
    const uint16_t* kb = kslab + (size_t)knext * 768;
    const uint16_t* vb = vslab + knext;
    uint16_t* Kbuf = &Ks[bufi][0];
    uint16_t* Vbuf = &Vs[bufi][0];
#pragma unroll
    for (int i = 0; i < 3; ++i) {
      gl_lds16(kb + koffs[i], Kbuf + (tid + 256 * i) * 8);
      gl_lds16(vb + voffs[i], Vbuf + (tid + 256 * i) * 8);
    }
  };

  float l_i[2][4] = {};
  f32x4 o_acc[2][6] = {};

  // rel double-buffer: always referenced BY NAME, compile-time indices only.
  float relvA[2][16], relvB[2][16];

#define LOADREL_TO(KNEXT, DST)                                               \
  {                                                                          \
    _Pragma("unroll") for (int r_ = 0; r_ < 4; ++r_) {                       \
      _Pragma("unroll") for (int nt_ = 0; nt_ < 4; ++nt_) {                  \
        DST[0][nt_ * 4 + r_] =                                               \
            relbase0[(size_t)r_ * 1024 + (KNEXT) + nt_ * 16];                \
        DST[1][nt_ * 4 + r_] =                                               \
            relbase1[(size_t)r_ * 1024 + (KNEXT) + nt_ * 16];                \
      }                                                                      \
    }                                                                        \
  }

  stage(0, 0);
  LOADREL_TO(0, relvA);

#define ATTN_TILE(KT, BUF, CURR, NXTR)                                       \
  {                                                                          \
    __syncthreads(); /* staging of cur drained; prior reads of nxt done */   \
    if ((KT) < 15) {                                                         \
      stage(((KT) + 1) * 64, (BUF) ^ 1);                                     \
      LOADREL_TO(((KT) + 1) * 64, NXTR); /* full tile of latency cover */    \
    }                                                                        \
    const uint16_t* KsC = &Ks[BUF][0];                                       \
    const uint16_t* VsC = &Vs[BUF][0];                                       \
    f32x4 s[2][4] = {};                                                      \
    __builtin_amdgcn_s_setprio(1);                                           \
    _Pragma("unroll") for (int ksi = 0; ksi < 3; ++ksi) {                    \
      _Pragma("unroll") for (int nt = 0; nt < 4; ++nt) {                     \
        const int row = nt * 16 + l16;                                       \
        const int c = ksi * 4 + quad;                                        \
        const int phys =                                                     \
            (ksi < 2) ? (c ^ (row & 7)) : (8 + ((c & 3) ^ (row & 3)));       \
        bf16x8 kf = *(const bf16x8*)&KsC[row * 96 + phys * 8];               \
        s[0][nt] = mfma16(qf[0][ksi], kf, s[0][nt]);                         \
        s[1][nt] = mfma16(qf[1][ksi], kf, s[1][nt]);                         \
      }                                                                      \
    }                                                                        \
    __builtin_amdgcn_s_setprio(0);                                           \
    const int khi = l16 >> 3;                                                \
    _Pragma("unroll") for (int st = 0; st < 2; ++st) {                       \
      float pv[16];                                                          \
      _Pragma("unroll") for (int nt = 0; nt < 4; ++nt)                       \
          _Pragma("unroll") for (int r = 0; r < 4; ++r)                      \
              pv[nt * 4 + r] = __builtin_amdgcn_exp2f(                       \
                  fmaf(CURR[st][nt * 4 + r], LOG2E, s[st][nt][r]));          \
      _Pragma("unroll") for (int r = 0; r < 4; ++r)                          \
          l_i[st][r] += (pv[r] + pv[4 + r]) + (pv[8 + r] + pv[12 + r]);      \
      _Pragma("unroll") for (int r = 0; r < 4; ++r) {                        \
        const int qloc = quad * 4 + r;                                       \
        const int rowoff = (st * 64 + w * 16 + qloc) * 64;                   \
        const int sw = qloc & 7;                                             \
        _Pragma("unroll") for (int nt = 0; nt < 4; ++nt) {                   \
          const int kc = 2 * nt + khi;                                       \
          Ps[rowoff + (((kc ^ sw) << 3) | l7)] = f2bf(pv[nt * 4 + r]);       \
        }                                                                    \
      }                                                                      \
    }                                                                        \
    asm volatile("s_waitcnt lgkmcnt(0)" ::: "memory");                       \
    __builtin_amdgcn_s_setprio(1);                                           \
    _Pragma("unroll") for (int ksi = 0; ksi < 2; ++ksi) {                    \
      const int phys = (ksi * 4 + quad) ^ l7;                                \
      bf16x8 pf0 = *(const bf16x8*)&Ps[(w * 16 + l16) * 64 + phys * 8];      \
      bf16x8 pf1 = *(const bf16x8*)&Ps[(64 + w * 16 + l16) * 64 + phys * 8]; \
      _Pragma("unroll") for (int jt = 0; jt < 6; ++jt) {                     \
        const int d = jt * 16 + l16;                                         \
        bf16x8 vf = *(const bf16x8*)&VsC[d * 64 + phys * 8];                 \
        o_acc[0][jt] = mfma16(pf0, vf, o_acc[0][jt]);                        \
        o_acc[1][jt] = mfma16(pf1, vf, o_acc[1][jt]);                        \
      }                                                                      \
    }                                                                        \
    __builtin_amdgcn_s_setprio(0);                                           \
  }

  for (int kt2 = 0; kt2 < 16; kt2 += 2) {
    ATTN_TILE(kt2, 0, relvA, relvB);
    ATTN_TILE(kt2 + 1, 1, relvB, relvA);
  }
#undef ATTN_TILE
#undef LOADREL_TO

  // epilogue: one DPP reduction per row, normalize, store bf16
#pragma unroll
  for (int st = 0; st < 2; ++st)
#pragma unroll
    for (int r = 0; r < 4; ++r) {
      float inv = 1.f / red16_add(l_i[st][r]);
      int row = q0 + st * 64 + w * 16 + quad * 4 + r;
#pragma unroll
      for (int jt = 0; jt < 6; ++jt) {
        int col = h * 96 + jt * 16 + l16;
        AO[(size_t)(b * 1024 + row) * 768 + col] = f2bf(o_acc[st][jt][r] * inv);
      }
    }
}

// ---------------------------------------------------------------------------
extern "C" void kernel_launch(void* const* d_in, const int* in_sizes, int n_in,
                              void* d_out, int out_size, void* d_ws,
                              size_t ws_size, hipStream_t stream) {
  const float* x   = (const float*)d_in[0];
  const float* y   = (const float*)d_in[1];
  const float* rel = (const float*)d_in[2];
  const float* Wq  = (const float*)d_in[5];
  const float* Wk  = (const float*)d_in[6];
  const float* Wv  = (const float*)d_in[7];
  const float* Wp  = (const float*)d_in[8];
  const float* bp  = (const float*)d_in[9];
  float* out = (float*)d_out;

  const size_t nBNC = (size_t)Bb * Nn * Cc;  // 6291456
  const size_t nW = (size_t)Cc * Cc;         // 589824

  char* ws = (char*)d_ws;
  size_t off = 0;
  auto alloc = [&](size_t bytes) {
    char* p = ws + off;
    off += (bytes + 255) & ~(size_t)255;
    return p;
  };
  uint16_t* xb  = (uint16_t*)alloc(nBNC * 2);
  uint16_t* yb  = (uint16_t*)alloc(nBNC * 2);
  uint16_t* wqb = (uint16_t*)alloc(nW * 2);
  uint16_t* wkb = (uint16_t*)alloc(nW * 2);
  uint16_t* wvb = (uint16_t*)alloc(nW * 2);
  uint16_t* wpb = (uint16_t*)alloc(nW * 2);
  uint16_t* Qb  = (uint16_t*)alloc(nBNC * 2);
  uint16_t* Kb  = (uint16_t*)alloc(nBNC * 2);
  uint16_t* Vtb = (uint16_t*)alloc(nBNC * 2);
  uint16_t* AOb = (uint16_t*)alloc(nBNC * 2);

  // 1. all conversions, one launch (14592 blocks exactly)
  const int cvtBlocks = (2 * NX4 + 4 * NW4) / 256;
  cvt_all<<<cvtBlocks, 256, 0, stream>>>(x, y, Wq, Wk, Wv, Wp, xb, yb, wqb,
                                         wkb, wvb, wpb);

  // 2. fused Q/KV projections (flat 1024, 128x96 tiles, XCD-banded)
  qkv_kernel<<<dim3(1024), 256, 0, stream>>>(xb, yb, wqb, wkb, wvb, Qb, Kb,
                                             Vtb);

  // 3. attention (flat 512 blocks, 256 threads, R7 + early rel prefetch)
  attn_kernel<<<dim3(512), 256, 0, stream>>>(Qb, Kb, Vtb, rel, AOb);

  // 4. output projection + bias (flat 512, 128x96 tiles, XCD-banded)
  proj_kernel<<<dim3(512), 256, 0, stream>>>(AOb, wpb, out, bp);
}

// Round 12
// 229.674 us; speedup vs baseline: 9.9933x; 1.4716x over previous
//
#include <hip/hip_runtime.h>
#include <hip/hip_bf16.h>
#include <cstdint>
#include <cstddef>

// ---------------------------------------------------------------------------
// Cross attention, B=8 N=1024 C=768 HEADS=8 HD=96, sr_ratio=1 path.
// R19 = revert to R9/R16 (230.8 us, session best). R17/R18's early-rel
// double-buffer spilled in two independent implementations (allocator pins
// arch-VGPR at 128 for this kernel shape); idea abandoned.
//   1. cvt_all: single launch; x,y -> bf16; Wq*QSC, Wk, Wv, Wp -> bf16
//   2. qkv_kernel: 128x96 tiles, 1024 blocks = 4/CU at 2-resident.
//      Q blocks + fused KV blocks (shared y-tile, dual B). n-tile == head.
//   3. flash attention: R7 structure + XCD-chunked decode + setprio (57us).
//   4. proj GEMM: 128x96 tiles, 512 blocks = 2/CU, shared gemm96_core.
// ---------------------------------------------------------------------------

using f32x4  = __attribute__((ext_vector_type(4))) float;
using bf16x8 = __attribute__((ext_vector_type(8))) __bf16;

constexpr int Bb = 8, Nn = 1024, Cc = 768;
constexpr float LOG2E = 1.4426950408889634f;
constexpr float QSC   = 0.10206207261596575f * 1.4426950408889634f;  // SCALE*log2e

__device__ __forceinline__ uint16_t f2bf(float f) {
  union { float f; uint32_t u; } v; v.f = f;
  return (uint16_t)((v.u + 0x7fffu + ((v.u >> 16) & 1u)) >> 16);  // RNE
}

__device__ __forceinline__ void gl_lds16(const void* g, void* l) {
  __builtin_amdgcn_global_load_lds(
      (const __attribute__((address_space(1))) void*)g,
      (__attribute__((address_space(3))) void*)l, 16, 0, 0);
}

__device__ __forceinline__ f32x4 mfma16(bf16x8 a, bf16x8 b, f32x4 c) {
  return __builtin_amdgcn_mfma_f32_16x16x32_bf16(a, b, c, 0, 0, 0);
}

// DPP row_ror sum over a 16-lane row (epilogue only)
template <int CTRL>
__device__ __forceinline__ float dpp_add(float v) {
  union { float f; int i; } u, r;
  u.f = v;
  r.i = __builtin_amdgcn_update_dpp(u.i, u.i, CTRL, 0xF, 0xF, false);
  return v + r.f;
}
__device__ __forceinline__ float red16_add(float v) {
  v = dpp_add<0x128>(v);  // row_ror:8
  v = dpp_add<0x124>(v);  // row_ror:4
  v = dpp_add<0x122>(v);  // row_ror:2
  v = dpp_add<0x121>(v);  // row_ror:1
  return v;
}

// ---------------------------------------------------------------------------
// Single conversion launch for all six tensors (flat-indexed in float4s).
constexpr int NX4 = (Bb * Nn * Cc) / 4;  // 1572864
constexpr int NW4 = (Cc * Cc) / 4;       // 147456
__global__ void cvt_all(const float* __restrict__ x, const float* __restrict__ y,
                        const float* __restrict__ wq, const float* __restrict__ wk,
                        const float* __restrict__ wv, const float* __restrict__ wp,
                        uint16_t* __restrict__ xb, uint16_t* __restrict__ yb,
                        uint16_t* __restrict__ dq, uint16_t* __restrict__ dk,
                        uint16_t* __restrict__ dv, uint16_t* __restrict__ dp) {
  int i = blockIdx.x * blockDim.x + threadIdx.x;
  const float* s; uint16_t* d; int off; float sc = 1.f;
  if (i < NX4) {
    s = x; d = xb; off = i;
  } else if (i < 2 * NX4) {
    s = y; d = yb; off = i - NX4;
  } else {
    int j = i - 2 * NX4;
    int wsel = j / NW4;
    off = j - wsel * NW4;
    switch (wsel) {
      case 0:  s = wq; d = dq; sc = QSC; break;
      case 1:  s = wk; d = dk; break;
      case 2:  s = wv; d = dv; break;
      default: s = wp; d = dp; break;
    }
  }
  float4 v = ((const float4*)s)[off];
  ushort4 o;
  o.x = f2bf(v.x * sc); o.y = f2bf(v.y * sc);
  o.z = f2bf(v.z * sc); o.w = f2bf(v.w * sc);
  ((ushort4*)d)[off] = o;
}

// ---------------------------------------------------------------------------
// GEMM core, 128x96 tile, BK=64, XOR-swizzled LDS, 2-barrier K-loop.
// Per wave: acc[4][3] (64x48 output), per K-step 7 staged chunks : 24 MFMA.
__device__ __forceinline__ void gemm96_core(const uint16_t* __restrict__ A,
                                            const uint16_t* __restrict__ Bt,
                                            uint16_t* As, uint16_t* Bs,
                                            int m0, int n0,
                                            f32x4 (&acc)[4][3]) {
  const int tid = threadIdx.x;
  const int lane = tid & 63, l16 = lane & 15, quad = lane >> 4;
  const int w = tid >> 6;
  const int wm = (w & 1) * 64, wn = (w >> 1) * 48;

  int soffA[4], soffB[3];
#pragma unroll
  for (int i = 0; i < 4; ++i) {
    int idx = tid + 256 * i;           // 1024 A chunks (128 rows x 8)
    int row = idx >> 3, pc = idx & 7;
    soffA[i] = row * 768 + (pc ^ (row & 7)) * 8;
  }
#pragma unroll
  for (int i = 0; i < 3; ++i) {
    int idx = tid + 256 * i;           // 768 B chunks (96 rows x 8)
    int row = idx >> 3, pc = idx & 7;
    soffB[i] = row * 768 + (pc ^ (row & 7)) * 8;
  }

  for (int k0 = 0; k0 < 768; k0 += 64) {
    __syncthreads();
#pragma unroll
    for (int i = 0; i < 4; ++i)
      gl_lds16(A + (size_t)m0 * 768 + k0 + soffA[i], &As[(tid + 256 * i) * 8]);
#pragma unroll
    for (int i = 0; i < 3; ++i)
      gl_lds16(Bt + (size_t)n0 * 768 + k0 + soffB[i], &Bs[(tid + 256 * i) * 8]);
    __syncthreads();
#pragma unroll
    for (int ks = 0; ks < 2; ++ks) {
      bf16x8 a[4], b[3];
      const int phys = (ks * 4 + quad) ^ (l16 & 7);
#pragma unroll
      for (int i = 0; i < 4; ++i)
        a[i] = *(const bf16x8*)&As[(wm + i * 16 + l16) * 64 + phys * 8];
#pragma unroll
      for (int j = 0; j < 3; ++j)
        b[j] = *(const bf16x8*)&Bs[(wn + j * 16 + l16) * 64 + phys * 8];
#pragma unroll
      for (int i = 0; i < 4; ++i)
#pragma unroll
        for (int j = 0; j < 3; ++j)
          acc[i][j] = mfma16(a[i], b[j], acc[i][j]);
    }
  }
}

// ---------------------------------------------------------------------------
// Fused Q/KV projections, 128x96 tiles. Flat grid 1024, XCD-banded:
//   xcd = id&7, jj = id>>3 (0..127); mt = xcd*8 + (jj&7) (0..63);
//   rest = jj>>3 (0..15): kind = rest>>3 (0=Q, 1=fused KV), nb = rest&7.
// 1024 blocks = 4/CU at 2-resident -> two full rounds, 100% packing.
// n0 = nb*96 == head boundary -> V epilogue decode is trivial (h = nb).
__global__ __launch_bounds__(256, 2) void qkv_kernel(
    const uint16_t* __restrict__ xb, const uint16_t* __restrict__ yb,
    const uint16_t* __restrict__ wq, const uint16_t* __restrict__ wk,
    const uint16_t* __restrict__ wv, uint16_t* __restrict__ Qb,
    uint16_t* __restrict__ Kb, uint16_t* __restrict__ Vt) {
  __shared__ uint16_t smem[20480];  // 40 KB: A(16K) + Bk(12K) + Bv(12K)
  const int id = blockIdx.x;
  const int xcd = id & 7, jj = id >> 3;
  const int mt = xcd * 8 + (jj & 7);
  const int rest = jj >> 3;          // 0..15
  const int kind = rest >> 3, nb = rest & 7;
  const int m0 = mt * 128, n0 = nb * 96;

  const int tid = threadIdx.x, lane = tid & 63;
  const int l16 = lane & 15, quad = lane >> 4, w = tid >> 6;
  const int wm = (w & 1) * 64, wn = (w >> 1) * 48;

  if (kind == 0) {
    // ---- Q: 128x96 GEMM, direct bf16 store ----
    f32x4 acc[4][3] = {};
    gemm96_core(xb, wq, smem, smem + 8192, m0, n0, acc);
#pragma unroll
    for (int i = 0; i < 4; ++i)
#pragma unroll
      for (int j = 0; j < 3; ++j) {
        int col = n0 + wn + j * 16 + l16;
#pragma unroll
        for (int r = 0; r < 4; ++r) {
          int row = m0 + wm + i * 16 + quad * 4 + r;
          Qb[(size_t)row * 768 + col] = f2bf(acc[i][j][r]);
        }
      }
    return;
  }

  // ---- fused KV: stage y once, two B tiles, dual accumulators ----
  uint16_t* As = smem;
  uint16_t* Bk = smem + 8192;
  uint16_t* Bv = smem + 14336;

  int soffA[4], soffB[3];
#pragma unroll
  for (int i = 0; i < 4; ++i) {
    int idx = tid + 256 * i;
    int row = idx >> 3, pc = idx & 7;
    soffA[i] = row * 768 + (pc ^ (row & 7)) * 8;
  }
#pragma unroll
  for (int i = 0; i < 3; ++i) {
    int idx = tid + 256 * i;
    int row = idx >> 3, pc = idx & 7;
    soffB[i] = row * 768 + (pc ^ (row & 7)) * 8;
  }

  f32x4 ak[4][3] = {}, av[4][3] = {};
  for (int k0 = 0; k0 < 768; k0 += 64) {
    __syncthreads();
#pragma unroll
    for (int i = 0; i < 4; ++i)
      gl_lds16(yb + (size_t)m0 * 768 + k0 + soffA[i], &As[(tid + 256 * i) * 8]);
#pragma unroll
    for (int i = 0; i < 3; ++i)
      gl_lds16(wk + (size_t)n0 * 768 + k0 + soffB[i], &Bk[(tid + 256 * i) * 8]);
#pragma unroll
    for (int i = 0; i < 3; ++i)
      gl_lds16(wv + (size_t)n0 * 768 + k0 + soffB[i], &Bv[(tid + 256 * i) * 8]);
    __syncthreads();

#pragma unroll
    for (int ks = 0; ks < 2; ++ks) {
      bf16x8 a[4], bk[3], bv[3];
      const int phys = (ks * 4 + quad) ^ (l16 & 7);
#pragma unroll
      for (int i = 0; i < 4; ++i)
        a[i] = *(const bf16x8*)&As[(wm + i * 16 + l16) * 64 + phys * 8];
#pragma unroll
      for (int j = 0; j < 3; ++j) {
        bk[j] = *(const bf16x8*)&Bk[(wn + j * 16 + l16) * 64 + phys * 8];
        bv[j] = *(const bf16x8*)&Bv[(wn + j * 16 + l16) * 64 + phys * 8];
      }
#pragma unroll
      for (int i = 0; i < 4; ++i)
#pragma unroll
        for (int j = 0; j < 3; ++j) {
          ak[i][j] = mfma16(a[i], bk[j], ak[i][j]);
          av[i][j] = mfma16(a[i], bv[j], av[i][j]);
        }
    }
  }

  // K epilogue: direct bf16 store
#pragma unroll
  for (int i = 0; i < 4; ++i)
#pragma unroll
    for (int j = 0; j < 3; ++j) {
      int col = n0 + wn + j * 16 + l16;
#pragma unroll
      for (int r = 0; r < 4; ++r) {
        int row = m0 + wm + i * 16 + quad * 4 + r;
        Kb[(size_t)row * 768 + col] = f2bf(ak[i][j][r]);
      }
    }

  // V epilogue: transpose in LDS (stride 130 pad), coalesced b128 stores.
  // n-tile == head: h = nb, hd = nl (0..95). 96*130 u16 = 24.4 KB <= 40 KB.
  __syncthreads();  // all LDS reads of the K-loop done; smem reusable
#pragma unroll
  for (int i = 0; i < 4; ++i)
#pragma unroll
    for (int j = 0; j < 3; ++j) {
      int ml = wm + i * 16 + quad * 4;   // local m (4 consecutive rows)
      int nl = wn + j * 16 + l16;        // local channel 0..95
      ushort4 pk;
      pk.x = f2bf(av[i][j][0]); pk.y = f2bf(av[i][j][1]);
      pk.z = f2bf(av[i][j][2]); pk.w = f2bf(av[i][j][3]);
      *(ushort4*)&smem[nl * 130 + ml] = pk;  // T[n][m], m-contiguous
    }
  __syncthreads();
  const int bidx = m0 >> 10, nseq0 = m0 & 1023;
#pragma unroll
  for (int pass = 0; pass < 6; ++pass) {
    int nl = pass * 16 + (tid >> 4);     // local channel 0..95
    int m = (tid & 15) * 8;              // m-chunk base
    bf16x8 v = *(const bf16x8*)&smem[nl * 130 + m];
    size_t o = (((size_t)(bidx * 8 + nb) * 96 + nl) << 10) + nseq0 + m;
    *(bf16x8*)(Vt + o) = v;              // 16 lanes x 16B contiguous
  }
}

// Output projection: 128x96 tiles via gemm96_core, flat grid 512 = 2/CU
// (XCD-banded: mt = xcd*8 + (jj&7) 0..63, nb = jj>>3 0..7; n0 = nb*96).
__global__ __launch_bounds__(256, 2) void proj_kernel(
    const uint16_t* __restrict__ A, const uint16_t* __restrict__ Bt,
    float* __restrict__ out, const float* __restrict__ bias) {
  __shared__ uint16_t smem[14336];    // 28 KB: As(16K) + Bs(12K)
  const int id = blockIdx.x;
  const int xcd = id & 7, jj = id >> 3;   // jj 0..63
  const int mt = xcd * 8 + (jj & 7);      // 0..63
  const int nb = jj >> 3;                 // 0..7
  const int m0 = mt * 128, n0 = nb * 96;
  const int tid = threadIdx.x, lane = tid & 63;
  const int l16 = lane & 15, quad = lane >> 4, w = tid >> 6;
  const int wm = (w & 1) * 64, wn = (w >> 1) * 48;

  f32x4 acc[4][3] = {};
  gemm96_core(A, Bt, smem, smem + 8192, m0, n0, acc);

  float bv[3];
#pragma unroll
  for (int j = 0; j < 3; ++j) bv[j] = bias[n0 + wn + j * 16 + l16];
#pragma unroll
  for (int i = 0; i < 4; ++i)
#pragma unroll
    for (int j = 0; j < 3; ++j) {
      int col = n0 + wn + j * 16 + l16;
#pragma unroll
      for (int r = 0; r < 4; ++r) {
        int row = m0 + wm + i * 16 + quad * 4 + r;
        out[(size_t)row * 768 + col] = acc[i][j][r] + bv[j];
      }
    }
}

// ---------------------------------------------------------------------------
// Flash attention: R7 structure + flat XCD-chunked grid decode + setprio.
// 256 threads, 4 waves x 2 strips, NO-MAX softmax, double-buffered K/V.
__global__ __launch_bounds__(256, 2) void attn_kernel(
    const uint16_t* __restrict__ Q,   // [B][N][C] bf16 (pre-scaled by QSC)
    const uint16_t* __restrict__ Kb,  // [B][N][C] bf16
    const uint16_t* __restrict__ Vt,  // [B*H][HD][N] bf16
    const float* __restrict__ rel,    // [H][N][N] f32
    uint16_t* __restrict__ AO) {      // [B][N][C] bf16
  __shared__ uint16_t Ks[2][64 * 96];   // 2 x 12 KB, mixed-XOR swizzle
  __shared__ uint16_t Vs[2][96 * 64];   // 2 x 12 KB, XOR swizzle
  __shared__ uint16_t Ps[128 * 64];     // 16 KB, XOR-swizzled chunks

  const int tid = threadIdx.x;
  // XCD-chunked bijective decode: swz = (id%8)*64 + id/8; h = swz>>6.
  const int id = blockIdx.x;
  const int swz = (id & 7) * 64 + (id >> 3);
  const int h  = swz >> 6;             // one head per XCD
  const int q0 = ((swz >> 3) & 7) * 128;
  const int b  = swz & 7;              // b fastest: rel-slice sharers adjacent
  const int bh = b * 8 + h;

  const int w = tid >> 6, lane = tid & 63;
  const int l16 = lane & 15, quad = lane >> 4;
  const int l7 = l16 & 7;

  // Q fragments in registers, 2 strips
  bf16x8 qf[2][3];
#pragma unroll
  for (int st = 0; st < 2; ++st) {
    const int qrow = q0 + st * 64 + w * 16 + l16;
    const uint16_t* qp =
        Q + ((size_t)(b * 1024 + qrow)) * 768 + h * 96 + quad * 8;
#pragma unroll
    for (int j = 0; j < 3; ++j) qf[st][j] = *(const bf16x8*)(qp + j * 32);
  }

  auto kSrc = [](int c) {
    int r = c / 12, pc = c % 12;
    int kc = (pc < 8) ? (pc ^ (r & 7)) : (8 + ((pc & 3) ^ (r & 3)));
    return r * 768 + kc * 8;
  };
  auto vSrc = [](int c) {
    int d = c >> 3, pc = c & 7;
    return d * 1024 + (pc ^ (d & 7)) * 8;
  };
  int koffs[3], voffs[3];
#pragma unroll
  for (int i = 0; i < 3; ++i) {
    koffs[i] = kSrc(tid + 256 * i);
    voffs[i] = vSrc(tid + 256 * i);
  }

  const uint16_t* kslab = Kb + ((size_t)(b * 1024)) * 768 + h * 96;
  const uint16_t* vslab = Vt + ((size_t)(bh * 96) << 10);
  const float* relbase0 =
      rel + ((size_t)h << 20) + ((size_t)(q0 + w * 16 + quad * 4) << 10) + l16;
  const float* relbase1 = relbase0 + (64 << 10);

  auto stage = [&](int knext, int bufi) {
    const uint16_t* kb = kslab + (size_t)knext * 768;
    const uint16_t* vb = vslab + knext;
    uint16_t* Kbuf = &Ks[bufi][0];
    uint16_t* Vbuf = &Vs[bufi][0];
#pragma unroll
    for (int i = 0; i < 3; ++i) {
      gl_lds16(kb + koffs[i], Kbuf + (tid + 256 * i) * 8);
      gl_lds16(vb + voffs[i], Vbuf + (tid + 256 * i) * 8);
    }
  };

  float relv[2][16];  // [strip][val] single buffer
  auto loadrel = [&](int knext) {
#pragma unroll
    for (int r = 0; r < 4; ++r)
#pragma unroll
      for (int nt = 0; nt < 4; ++nt) {
        relv[0][nt * 4 + r] = relbase0[(size_t)r * 1024 + knext + nt * 16];
        relv[1][nt * 4 + r] = relbase1[(size_t)r * 1024 + knext + nt * 16];
      }
  };

  float l_i[2][4] = {};
  f32x4 o_acc[2][6] = {};

  stage(0, 0);
  loadrel(0);

#pragma unroll 2
  for (int kt = 0; kt < 16; ++kt) {
    const int cur = kt & 1, nxt = (kt + 1) & 1;
    __syncthreads();  // staging of cur drained; prior reads of nxt done
    if (kt < 15) stage((kt + 1) * 64, nxt);
    const uint16_t* KsC = &Ks[cur][0];
    const uint16_t* VsC = &Vs[cur][0];

    // S strips (2 x 16q x 64k): each K B-frag read feeds both strips
    f32x4 s[2][4] = {};
    __builtin_amdgcn_s_setprio(1);
#pragma unroll
    for (int ksi = 0; ksi < 3; ++ksi) {
#pragma unroll
      for (int nt = 0; nt < 4; ++nt) {
        const int row = nt * 16 + l16;
        const int c = ksi * 4 + quad;
        const int phys =
            (ksi < 2) ? (c ^ (row & 7)) : (8 + ((c & 3) ^ (row & 3)));
        bf16x8 kf = *(const bf16x8*)&KsC[row * 96 + phys * 8];
        s[0][nt] = mfma16(qf[0][ksi], kf, s[0][nt]);
        s[1][nt] = mfma16(qf[1][ksi], kf, s[1][nt]);
      }
    }
    __builtin_amdgcn_s_setprio(0);

    // softmax (no max) + P scatter per strip; consumes relv[st]
    const int khi = l16 >> 3;
#pragma unroll
    for (int st = 0; st < 2; ++st) {
      float pv[16];
#pragma unroll
      for (int nt = 0; nt < 4; ++nt)
#pragma unroll
        for (int r = 0; r < 4; ++r)
          pv[nt * 4 + r] = __builtin_amdgcn_exp2f(
              fmaf(relv[st][nt * 4 + r], LOG2E, s[st][nt][r]));
#pragma unroll
      for (int r = 0; r < 4; ++r)
        l_i[st][r] += (pv[r] + pv[4 + r]) + (pv[8 + r] + pv[12 + r]);
#pragma unroll
      for (int r = 0; r < 4; ++r) {
        const int qloc = quad * 4 + r;
        const int rowoff = (st * 64 + w * 16 + qloc) * 64;
        const int sw = qloc & 7;
#pragma unroll
        for (int nt = 0; nt < 4; ++nt) {
          const int kc = 2 * nt + khi;
          Ps[rowoff + (((kc ^ sw) << 3) | l7)] = f2bf(pv[nt * 4 + r]);
        }
      }
    }

    // relv dead: prefetch next tile's bias (hides behind PV + barrier)
    if (kt < 15) loadrel((kt + 1) * 64);

    asm volatile("s_waitcnt lgkmcnt(0)" ::: "memory");  // wave-internal W->R

    // O strips (2 x 16q x 96d): each V B-frag read feeds both strips
    __builtin_amdgcn_s_setprio(1);
#pragma unroll
    for (int ksi = 0; ksi < 2; ++ksi) {
      const int phys = (ksi * 4 + quad) ^ l7;
      bf16x8 pf0 = *(const bf16x8*)&Ps[(w * 16 + l16) * 64 + phys * 8];
      bf16x8 pf1 = *(const bf16x8*)&Ps[(64 + w * 16 + l16) * 64 + phys * 8];
#pragma unroll
      for (int jt = 0; jt < 6; ++jt) {
        const int d = jt * 16 + l16;
        bf16x8 vf = *(const bf16x8*)&VsC[d * 64 + phys * 8];  // d&7 == l7
        o_acc[0][jt] = mfma16(pf0, vf, o_acc[0][jt]);
        o_acc[1][jt] = mfma16(pf1, vf, o_acc[1][jt]);
      }
    }
    __builtin_amdgcn_s_setprio(0);
  }

  // epilogue: one DPP reduction per row, normalize, store bf16
#pragma unroll
  for (int st = 0; st < 2; ++st)
#pragma unroll
    for (int r = 0; r < 4; ++r) {
      float inv = 1.f / red16_add(l_i[st][r]);
      int row = q0 + st * 64 + w * 16 + quad * 4 + r;
#pragma unroll
      for (int jt = 0; jt < 6; ++jt) {
        int col = h * 96 + jt * 16 + l16;
        AO[(size_t)(b * 1024 + row) * 768 + col] = f2bf(o_acc[st][jt][r] * inv);
      }
    }
}

// ---------------------------------------------------------------------------
extern "C" void kernel_launch(void* const* d_in, const int* in_sizes, int n_in,
                              void* d_out, int out_size, void* d_ws,
                              size_t ws_size, hipStream_t stream) {
  const float* x   = (const float*)d_in[0];
  const float* y   = (const float*)d_in[1];
  const float* rel = (const float*)d_in[2];
  const float* Wq  = (const float*)d_in[5];
  const float* Wk  = (const float*)d_in[6];
  const float* Wv  = (const float*)d_in[7];
  const float* Wp  = (const float*)d_in[8];
  const float* bp  = (const float*)d_in[9];
  float* out = (float*)d_out;

  const size_t nBNC = (size_t)Bb * Nn * Cc;  // 6291456
  const size_t nW = (size_t)Cc * Cc;         // 589824

  char* ws = (char*)d_ws;
  size_t off = 0;
  auto alloc = [&](size_t bytes) {
    char* p = ws + off;
    off += (bytes + 255) & ~(size_t)255;
    return p;
  };
  uint16_t* xb  = (uint16_t*)alloc(nBNC * 2);
  uint16_t* yb  = (uint16_t*)alloc(nBNC * 2);
  uint16_t* wqb = (uint16_t*)alloc(nW * 2);
  uint16_t* wkb = (uint16_t*)alloc(nW * 2);
  uint16_t* wvb = (uint16_t*)alloc(nW * 2);
  uint16_t* wpb = (uint16_t*)alloc(nW * 2);
  uint16_t* Qb  = (uint16_t*)alloc(nBNC * 2);
  uint16_t* Kb  = (uint16_t*)alloc(nBNC * 2);
  uint16_t* Vtb = (uint16_t*)alloc(nBNC * 2);
  uint16_t* AOb = (uint16_t*)alloc(nBNC * 2);

  // 1. all conversions, one launch (14592 blocks exactly)
  const int cvtBlocks = (2 * NX4 + 4 * NW4) / 256;
  cvt_all<<<cvtBlocks, 256, 0, stream>>>(x, y, Wq, Wk, Wv, Wp, xb, yb, wqb,
                                         wkb, wvb, wpb);

  // 2. fused Q/KV projections (flat 1024, 128x96 tiles, XCD-banded)
  qkv_kernel<<<dim3(1024), 256, 0, stream>>>(xb, yb, wqb, wkb, wvb, Qb, Kb,
                                             Vtb);

  // 3. attention (flat 512 blocks, 256 threads, R7 structure + XCD decode)
  attn_kernel<<<dim3(512), 256, 0, stream>>>(Qb, Kb, Vtb, rel, AOb);

  // 4. output projection + bias (flat 512, 128x96 tiles, XCD-banded)
  proj_kernel<<<dim3(512), 256, 0, stream>>>(AOb, wpb, out, bp);
}